// Round 12
// baseline (729.172 us; speedup 1.0000x reference)
//
#include <hip/hip_runtime.h>
#include <math.h>

#define NF 8
#define SS 5
#define DIN 64
#define KSTEP 3
#define BT 32
#define FH_PAD 68             // padded row (bank spread, 16B-aligned rows)
#define FSTR (SS*FH_PAD)      // 340 (340%32=20 -> 8 distinct start banks)
#define HOPSTR (NF*FSTR)      // 2720 floats per hop block
#define NS_OFF (KSTEP*HOPSTR) // ws: nsqh [3][8][5] after fh blocks

// exp(-(sqf+sqh-2cr)/3.2) = 2^(CC*cr - CS*sqf - CS*sqh)
#define CS 0.45084219902780109f
#define CC 0.90168439805560218f

__device__ __forceinline__ float fexp2(float x) {
#if __has_builtin(__builtin_amdgcn_exp2f)
  return __builtin_amdgcn_exp2f(x);
#else
  return exp2f(x);
#endif
}

// symmetric 5x5 index (i<=j): base i*(9-i)/2 + j ; folds at compile time
__device__ __forceinline__ constexpr int midx(int i, int j) {
  return (i <= j) ? (i*(9-i))/2 + j : (j*(9-j))/2 + i;
}

// e in [0,15) -> (i,j) upper-triangle entry (runtime, used only for LDS ptrs)
__device__ __forceinline__ void tri_ij(int e, int& i, int& j) {
  int i_ = (e >= 5) + (e >= 9) + (e >= 12) + (e >= 14);
  int off = (i_ == 0) ? 0 : (i_ == 1) ? 4 : (i_ == 2) ? 7 : (i_ == 3) ? 9 : 10;
  i = i_; j = e - off;
}

__global__ __launch_bounds__(256) void hidden_prep(
    const float* __restrict__ adjs_hidden,
    const float* __restrict__ features_hidden,
    float* __restrict__ ws)
{
  __shared__ float Ah[NF][SS][SS];
  __shared__ float buf[2][NF][SS][DIN];
  const int t = threadIdx.x;

  if (t < NF*SS*SS) ((float*)Ah)[t] = 0.0f;
  for (int i = t; i < NF*SS*DIN; i += 256) ((float*)buf[0])[i] = features_hidden[i];
  __syncthreads();
  if (t < NF*10) {
    const int iu0[10] = {0,0,0,0,1,1,1,2,2,3};
    const int iu1[10] = {1,2,3,4,2,3,4,3,4,4};
    int f = t / 10, k = t % 10;
    float sg = 1.0f / (1.0f + expf(-adjs_hidden[t]));
    Ah[f][iu0[k]][iu1[k]] = sg;
    Ah[f][iu1[k]][iu0[k]] = sg;
  }
  __syncthreads();

  int cur = 0;
  for (int h = 0; h < KSTEP; ++h) {
    // padded fh for this hop: ws[h*HOPSTR + f*FSTR + s*FH_PAD + d]
    for (int i = t; i < NF*SS*DIN; i += 256) {
      int f = i / (SS*DIN), s = (i / DIN) % SS, d = i % DIN;
      ws[h*HOPSTR + f*FSTR + s*FH_PAD + d] = buf[cur][f][s][d];
    }
    // negated, pre-scaled sq_h
    if (t < NF*SS) {
      float acc = 0.0f;
      int f = t / SS, s = t % SS;
      for (int d = 0; d < DIN; ++d) { float v = buf[cur][f][s][d]; acc = fmaf(v, v, acc); }
      ws[NS_OFF + h*NF*SS + t] = -acc * CS;
    }
    if (h + 1 < KSTEP) {
      __syncthreads();
      for (int i = t; i < NF*SS*DIN; i += 256) {
        int f = i / (SS*DIN), s = (i / DIN) % SS, d = i % DIN;
        float acc = 0.0f;
        for (int j = 0; j < SS; ++j) acc = fmaf(Ah[f][s][j], buf[cur][f][j][d], acc);
        buf[cur^1][f][s][d] = acc;
      }
      __syncthreads();
      cur ^= 1;
    }
  }
}

// r7 skeleton (one barrier, hop loop = unroll 1, proven 88-VGPR) with the
// redundant fv*fv sqf fold replaced by: octet-coop Gram M0 (LDS) + per-thread
// STATIC-indexed M-chain (dm1 = diag(A*M0*A^T), dm2 = diag(A*M1*A^T)).
// Cuts ~480 net FMA/thread from the VALU-bound wall.
__global__ __launch_bounds__(256) void kc_main(
    const float* __restrict__ adjs,
    const float* __restrict__ feature,
    const int* __restrict__ idxs,
    const float* __restrict__ ws,
    float* __restrict__ out,
    int B, int N)
{
  __shared__ float fh[KSTEP*HOPSTR];     // 32640 B, padded conflict-free
  __shared__ float nsqh[KSTEP*NF*SS];    // 480 B
  __shared__ float fS[BT][SS][FH_PAD];   // 43520 B
  __shared__ float Msh[BT][16];          // 2048 B (Gram M0) -> ~78.7 KB, 2 blk/CU

  const int t    = threadIdx.x;
  const int lane = t & 63;
  const int wv   = t >> 6;     // wave id 0..3
  const int b_i  = t >> 3;     // octet = one b
  const int f_   = t & 7;      // filter / d-slice owner
  const int bg   = blockIdx.x * BT + b_i;
  const bool valid = bg < B;

  // --- async fh staging: 8160 floats in 1024B chunks, waves interleaved ---
  for (int c = wv; c < 32; c += 4) {
    const int nfl = (c == 31) ? 224 : 256;   // floats in this chunk
    if (lane * 4 < nfl)
      __builtin_amdgcn_global_load_lds(
          (const __attribute__((address_space(1))) void*)(ws + c*256 + lane*4),
          (__attribute__((address_space(3))) void*)(fh + c*256), 16, 0, 0);
  }
  // nsqh (120 floats) via plain staging
  if (t < KSTEP*NF*SS) nsqh[t] = ws[NS_OFF + t];

  // --- adj into registers (octet-broadcast loads, L1/L2-cached) ---
  float A_[SS*SS];
  #pragma unroll
  for (int k = 0; k < SS*SS; ++k)
    A_[k] = valid ? adjs[(size_t)bg*(SS*SS) + k] : 0.0f;

  // --- gather: thread fetches d-columns [8f_, 8f_+8) of its b into fS ---
  #pragma unroll
  for (int m = 0; m < SS; ++m) {
    int id = valid ? idxs[bg*SS + m] : -1;
    #pragma unroll
    for (int h2 = 0; h2 < 2; ++h2) {
      float4 v = make_float4(0.f, 0.f, 0.f, 0.f);
      if ((unsigned)id < (unsigned)N)
        v = reinterpret_cast<const float4*>(feature)[(size_t)id*16 + f_*2 + h2];
      *reinterpret_cast<float4*>(&fS[b_i][m][f_*8 + h2*4]) = v;
    }
  }

  __syncthreads();  // drains vmcnt (async fh) + lgkm; fS/nsqh visible

  // ---- M0 Gram, octet-cooperative: lane f_ computes entries f_ and f_+8 ----
  {
    int i0, j0, i1, j1;
    tri_ij(f_, i0, j0);
    const int e1 = f_ + 8;
    tri_ij(e1 > 14 ? 14 : e1, i1, j1);
    const float* fb = &fS[b_i][0][0];
    const float* r0 = fb + i0*FH_PAD;
    const float* r1 = fb + j0*FH_PAD;
    const float* r2 = fb + i1*FH_PAD;
    const float* r3 = fb + j1*FH_PAD;
    float m0 = 0.0f, m1 = 0.0f;
    #pragma unroll
    for (int d4 = 0; d4 < 16; ++d4) {
      float4 va = *reinterpret_cast<const float4*>(&r0[d4*4]);
      float4 vb = *reinterpret_cast<const float4*>(&r1[d4*4]);
      float4 vc = *reinterpret_cast<const float4*>(&r2[d4*4]);
      float4 vd = *reinterpret_cast<const float4*>(&r3[d4*4]);
      m0 = fmaf(va.x, vb.x, m0); m0 = fmaf(va.y, vb.y, m0);
      m0 = fmaf(va.z, vb.z, m0); m0 = fmaf(va.w, vb.w, m0);
      m1 = fmaf(vc.x, vd.x, m1); m1 = fmaf(vc.y, vd.y, m1);
      m1 = fmaf(vc.z, vd.z, m1); m1 = fmaf(vc.w, vd.w, m1);
    }
    Msh[b_i][f_] = m0;
    if (e1 < 15) Msh[b_i][e1] = m1;
  }
  // octet-local write->read, same wave: no barrier

  // ---- per-thread STATIC M-chain: dm0/dm1/dm2 (pre-scaled by CS) ----
  float dm0[SS], dm1[SS], dm2[SS];
  {
    float m0r[15];
    #pragma unroll
    for (int e = 0; e < 15; ++e) m0r[e] = Msh[b_i][e];
    #pragma unroll
    for (int m = 0; m < SS; ++m) dm0[m] = CS * m0r[midx(m, m)];

    // T = A * M0
    float T[SS][SS];
    #pragma unroll
    for (int i = 0; i < SS; ++i)
      #pragma unroll
      for (int l = 0; l < SS; ++l) {
        float acc = 0.0f;
        #pragma unroll
        for (int k = 0; k < SS; ++k) acc = fmaf(A_[i*SS+k], m0r[midx(k, l)], acc);
        T[i][l] = acc;
      }
    // M1 = T * A^T (symmetric, 15 entries)
    float M1[15];
    #pragma unroll
    for (int i = 0; i < SS; ++i)
      #pragma unroll
      for (int j = i; j < SS; ++j) {
        float acc = 0.0f;
        #pragma unroll
        for (int l = 0; l < SS; ++l) acc = fmaf(T[i][l], A_[j*SS+l], acc);
        M1[midx(i, j)] = acc;
      }
    #pragma unroll
    for (int m = 0; m < SS; ++m) dm1[m] = CS * M1[midx(m, m)];

    // T2 = A * M1 ; dm2 = diag(T2 * A^T)
    #pragma unroll
    for (int m = 0; m < SS; ++m) {
      float r[SS];
      #pragma unroll
      for (int l = 0; l < SS; ++l) r[l] = 0.0f;
      #pragma unroll
      for (int k = 0; k < SS; ++k) {
        float amk = A_[m*SS+k];
        #pragma unroll
        for (int l = 0; l < SS; ++l) r[l] = fmaf(amk, M1[midx(k, l)], r[l]);
      }
      float acc = 0.0f;
      #pragma unroll
      for (int l = 0; l < SS; ++l) acc = fmaf(r[l], A_[m*SS+l], acc);
      dm2[m] = CS * acc;
    }
  }

  float total[SS][SS];
  #pragma unroll
  for (int m = 0; m < SS; ++m)
    #pragma unroll
    for (int s = 0; s < SS; ++s) total[m][s] = 0.0f;

  #pragma unroll 1
  for (int hop = 0; hop < KSTEP; ++hop) {
    if (hop) {
      // f <- adjs @ f : octet-local (thread owns d-columns [8f_,8f_+8))
      const int dbase = f_ * 8;
      float fo[SS][8];
      #pragma unroll
      for (int j = 0; j < SS; ++j)
        #pragma unroll
        for (int h2 = 0; h2 < 2; ++h2) {
          float4 v = *reinterpret_cast<const float4*>(&fS[b_i][j][dbase + h2*4]);
          fo[j][h2*4+0] = v.x; fo[j][h2*4+1] = v.y;
          fo[j][h2*4+2] = v.z; fo[j][h2*4+3] = v.w;
        }
      #pragma unroll
      for (int m = 0; m < SS; ++m) {
        float fn[8];
        #pragma unroll
        for (int dd = 0; dd < 8; ++dd) fn[dd] = 0.0f;
        #pragma unroll
        for (int j = 0; j < SS; ++j)
          #pragma unroll
          for (int dd = 0; dd < 8; ++dd)
            fn[dd] = fmaf(A_[m*SS + j], fo[j][dd], fn[dd]);
        #pragma unroll
        for (int h2 = 0; h2 < 2; ++h2) {
          float4 v = make_float4(fn[h2*4+0], fn[h2*4+1], fn[h2*4+2], fn[h2*4+3]);
          *reinterpret_cast<float4*>(&fS[b_i][m][dbase + h2*4]) = v;
        }
      }
      // no barrier: octet-local, same wave
    }

    // cross only (sqf comes from the M-chain)
    float cr[SS][SS];
    #pragma unroll
    for (int m = 0; m < SS; ++m)
      #pragma unroll
      for (int s = 0; s < SS; ++s) cr[m][s] = 0.0f;

    const float* fhh = &fh[hop*HOPSTR + f_*FSTR];
    #pragma unroll
    for (int d4 = 0; d4 < 16; ++d4) {
      float4 fv[SS], hv[SS];
      #pragma unroll
      for (int m = 0; m < SS; ++m)
        fv[m] = *reinterpret_cast<const float4*>(&fS[b_i][m][d4*4]);
      #pragma unroll
      for (int s = 0; s < SS; ++s)
        hv[s] = *reinterpret_cast<const float4*>(&fhh[s*FH_PAD + d4*4]);
      #pragma unroll
      for (int m = 0; m < SS; ++m)
        #pragma unroll
        for (int s = 0; s < SS; ++s) {
          cr[m][s] = fmaf(fv[m].x, hv[s].x, cr[m][s]);
          cr[m][s] = fmaf(fv[m].y, hv[s].y, cr[m][s]);
          cr[m][s] = fmaf(fv[m].z, hv[s].z, cr[m][s]);
          cr[m][s] = fmaf(fv[m].w, hv[s].w, cr[m][s]);
        }
    }

    float sqf2[SS];
    #pragma unroll
    for (int m = 0; m < SS; ++m)
      sqf2[m] = (hop == 0) ? dm0[m] : (hop == 1) ? dm1[m] : dm2[m];

    #pragma unroll
    for (int m = 0; m < SS; ++m) {
      #pragma unroll
      for (int s = 0; s < SS; ++s) {
        float nh = nsqh[hop*NF*SS + f_*SS + s];
        float arg = fmaf(CC, cr[m][s], nh - sqf2[m]);  // <= 0 always
        total[m][s] += fexp2(arg);
      }
    }
  }

  // greedy matching: row 0 -> col 0; rows 1..4 argmax over untaken cols
  float res = total[0][0];
  int taken = 1;
  #pragma unroll
  for (int r = 1; r < SS; ++r) {
    float best = -2.0f; int bi = 0;
    #pragma unroll
    for (int s = 0; s < SS; ++s) {
      float sc = ((taken >> s) & 1) ? -1.0f : total[r][s];
      if (sc > best) { best = sc; bi = s; }
    }
    res += best;
    taken |= (1 << bi);
  }
  if (valid) out[(size_t)bg*NF + f_] = res;
}

extern "C" void kernel_launch(void* const* d_in, const int* in_sizes, int n_in,
                              void* d_out, int out_size, void* d_ws, size_t ws_size,
                              hipStream_t stream) {
  const float* adjs            = (const float*)d_in[0];
  const float* feature         = (const float*)d_in[1];
  const int*   idxs            = (const int*)d_in[2];
  const float* adjs_hidden     = (const float*)d_in[3];
  const float* features_hidden = (const float*)d_in[4];
  float* out = (float*)d_out;
  float* ws  = (float*)d_ws;

  const int B = in_sizes[0] / (SS*SS);
  const int N = in_sizes[1] / DIN;

  hipLaunchKernelGGL(hidden_prep, dim3(1), dim3(256), 0, stream,
                     adjs_hidden, features_hidden, ws);
  const int nblk = (B + BT - 1) / BT;
  hipLaunchKernelGGL(kc_main, dim3(nblk), dim3(256), 0, stream,
                     adjs, feature, idxs, ws, out, B, N);
}